// Round 2
// baseline (4510.154 us; speedup 1.0000x reference)
//
#include <hip/hip_runtime.h>
#include <cstdint>
#include <cstddef>

typedef unsigned short u16;
typedef float f32x4 __attribute__((ext_vector_type(4)));
typedef short s16x8 __attribute__((ext_vector_type(8)));
typedef __bf16 bf16x8 __attribute__((ext_vector_type(8)));

#define DEVINL __device__ __forceinline__

DEVINL float bf2f(u16 u){ union{unsigned int i; float f;} c; c.i=((unsigned int)u)<<16; return c.f; }
DEVINL u16 f2bf(float f){ union{float f; unsigned int i;} c; c.f=f; unsigned int u=c.i;
                          u += 0x7FFF + ((u>>16)&1); return (u16)(u>>16); }

DEVINL f32x4 mfma16(bf16x8 a, bf16x8 b, f32x4 c){
  return __builtin_amdgcn_mfma_f32_16x16x32_bf16(a, b, c, 0, 0, 0);
}

typedef const __attribute__((address_space(1))) void* gas1p;
typedef __attribute__((address_space(3))) void* as3p;
DEVINL void async16(const void* g, void* l){
  __builtin_amdgcn_global_load_lds((gas1p)g, (as3p)l, 16, 0, 0);
}

// ---------------- weight prep ----------------

__global__ void cvt_bf16(const float* __restrict__ in, u16* __restrict__ out, int n){
  int i = (blockIdx.x * 256 + threadIdx.x) * 4;
  if (i >= n) return;
  float4 v = *(const float4*)(in + i);
  short4 sv = make_short4((short)f2bf(v.x), (short)f2bf(v.y), (short)f2bf(v.z), (short)f2bf(v.w));
  *(short4*)(out + i) = sv;
}

// W [K][N] f32  ->  WT [N][K] bf16   (grid: (N/32, K/32, nmat), block (32,8))
__global__ __launch_bounds__(256) void trans_w(const float* __restrict__ W, u16* __restrict__ WT,
                                               int K, int N){
  __shared__ float t[32][33];
  const float* Wm = W  + (size_t)blockIdx.z * K * N;
  u16*         Tm = WT + (size_t)blockIdx.z * K * N;
  const int x = threadIdx.x, y = threadIdx.y;
  const int n0 = blockIdx.x * 32, k0 = blockIdx.y * 32;
#pragma unroll
  for (int j = 0; j < 32; j += 8)
    t[y + j][x] = Wm[(size_t)(k0 + y + j) * N + n0 + x];
  __syncthreads();
#pragma unroll
  for (int j = 0; j < 32; j += 8)
    Tm[(size_t)(n0 + y + j) * K + k0 + x] = f2bf(t[x][y + j]);
}

// ---------------- main GEMM: C[M,N] = A[M,K](bf16) * BT[N,K](bf16)^T ----------------
// fuse: 0 bias->bf16, 1 relu->bf16, 2 gelu->bf16, 3 bias->f32, 4 resid+bias->f32,
//       5 resid+bias+pos->f32 (N must be 1024)

__global__ __launch_bounds__(256) void gemm128(
    const u16* __restrict__ A, const u16* __restrict__ BT,
    const float* __restrict__ bias, const float* __restrict__ resid,
    const float* __restrict__ pos, void* __restrict__ out,
    int M, int N, int K, int fuse)
{
  __shared__ u16 As[2][4096];
  __shared__ u16 Bs[2][4096];
  const int tid = threadIdx.x;
  const int bn = blockIdx.x, bm = blockIdx.y;
  const int lane = tid & 63, wid = tid >> 6;
  const int lr = lane & 15, lk = lane >> 4;
  const int wm = (wid >> 1) * 64, wn = (wid & 1) * 64;

  f32x4 acc[4][4] = {};

  const int r0 = tid >> 2;
  const int c0 = (tid & 3) * 8;
  const u16* Ab = A  + (size_t)(bm * 128 + r0) * K + c0;
  const u16* Bb = BT + (size_t)(bn * 128 + r0) * K + c0;
  const size_t rstep = (size_t)64 * K;
  const int nk = K >> 5;

  async16(Ab,         &As[0][tid * 8]);
  async16(Ab + rstep, &As[0][2048 + tid * 8]);
  async16(Bb,         &Bs[0][tid * 8]);
  async16(Bb + rstep, &Bs[0][2048 + tid * 8]);

  int cur = 0;
  for (int kt = 0; kt < nk; ++kt){
    __syncthreads();
    if (kt + 1 < nk){
      const u16* An = Ab + (size_t)(kt + 1) * 32;
      const u16* Bn = Bb + (size_t)(kt + 1) * 32;
      u16* Asn = &As[cur ^ 1][0];
      u16* Bsn = &Bs[cur ^ 1][0];
      async16(An,         Asn + tid * 8);
      async16(An + rstep, Asn + 2048 + tid * 8);
      async16(Bn,         Bsn + tid * 8);
      async16(Bn + rstep, Bsn + 2048 + tid * 8);
    }
    bf16x8 af[4], bfv[4];
#pragma unroll
    for (int i = 0; i < 4; ++i)
      af[i] = *(const bf16x8*)&As[cur][(wm + i * 16 + lr) * 32 + lk * 8];
#pragma unroll
    for (int j = 0; j < 4; ++j)
      bfv[j] = *(const bf16x8*)&Bs[cur][(wn + j * 16 + lr) * 32 + lk * 8];
#pragma unroll
    for (int i = 0; i < 4; ++i)
#pragma unroll
      for (int j = 0; j < 4; ++j)
        acc[i][j] = mfma16(af[i], bfv[j], acc[i][j]);
    cur ^= 1;
  }

  const int gm0 = bm * 128 + wm, gn0 = bn * 128 + wn;
  float* outf = (float*)out;
  u16*   outb = (u16*)out;
#pragma unroll
  for (int i = 0; i < 4; ++i){
#pragma unroll
    for (int j = 0; j < 4; ++j){
      const int col = gn0 + j * 16 + lr;
      const float bv = bias ? bias[col] : 0.f;
#pragma unroll
      for (int r = 0; r < 4; ++r){
        const int row = gm0 + i * 16 + lk * 4 + r;
        const size_t idx = (size_t)row * N + col;
        float v = acc[i][j][r] + bv;
        if (fuse == 1)      v = fmaxf(v, 0.f);
        else if (fuse == 2) v = 0.5f * v * (1.f + erff(v * 0.70710678118654752f));
        else if (fuse == 4) v += resid[idx];
        else if (fuse == 5) v += resid[idx] + pos[((row & 31) << 10) + col];
        if (fuse >= 3) outf[idx] = v;
        else           outb[idx] = f2bf(v);
      }
    }
  }
}

// ---------------- LayerNorm: fp32 in -> bf16 out ----------------

__global__ __launch_bounds__(256) void ln_k(
    const float* __restrict__ x, const float* __restrict__ g,
    const float* __restrict__ b, u16* __restrict__ out)
{
  const int row = blockIdx.x;
  const float* xr = x + (size_t)row * 1024;
  const int tid = threadIdx.x;
  float4 v = *(const float4*)(xr + tid * 4);
  float s  = v.x + v.y + v.z + v.w;
  float ss = v.x * v.x + v.y * v.y + v.z * v.z + v.w * v.w;
#pragma unroll
  for (int m = 1; m < 64; m <<= 1){ s += __shfl_xor(s, m, 64); ss += __shfl_xor(ss, m, 64); }
  __shared__ float red[8];
  if ((tid & 63) == 0){ red[tid >> 6] = s; red[4 + (tid >> 6)] = ss; }
  __syncthreads();
  s  = red[0] + red[1] + red[2] + red[3];
  ss = red[4] + red[5] + red[6] + red[7];
  const float mu = s * (1.f / 1024.f);
  const float rs = rsqrtf(ss * (1.f / 1024.f) - mu * mu + 1e-5f);
  float4 gg = *(const float4*)(g + tid * 4);
  float4 bb = *(const float4*)(b + tid * 4);
  short4 sv = make_short4((short)f2bf((v.x - mu) * rs * gg.x + bb.x),
                          (short)f2bf((v.y - mu) * rs * gg.y + bb.y),
                          (short)f2bf((v.z - mu) * rs * gg.z + bb.z),
                          (short)f2bf((v.w - mu) * rs * gg.w + bb.w));
  *(short4*)(out + (size_t)row * 1024 + tid * 4) = sv;
}

// ---------------- attention: one wave per (b,h), S=32, HD=64 ----------------

__global__ __launch_bounds__(256) void attn_k(
    const u16* __restrict__ Q, const u16* __restrict__ Kx,
    const u16* __restrict__ V, const u16* __restrict__ rel,
    u16* __restrict__ O)
{
  __shared__ char smem[65536];
  const int tid = threadIdx.x;
  const int wid = tid >> 6, lane = tid & 63;
  const int lr = lane & 15, lk = lane >> 4;
  char* sw = smem + wid * 16384;
  float* P = (float*)sw;            // [32][68] f32
  u16*  AL = (u16*)(sw + 8704);     // [32][40] bf16 (attn probs)
  u16*  VT = (u16*)(sw + 11264);    // [64][40] bf16 (V^T)

  const int pair = blockIdx.x * 4 + wid;
  const int b = pair >> 4, h = pair & 15;
  const size_t base = (size_t)b * 32768 + (size_t)h * 64;
  const u16* q  = Q  + base;
  const u16* kk = Kx + base;
  const u16* v  = V  + base;
  u16* o = O + base;

  s16x8 vv[4];
#pragma unroll
  for (int j = 0; j < 4; ++j){
    const int e = j * 64 + lane;
    const int ki = e >> 3, d0 = (e & 7) * 8;
    vv[j] = *(const s16x8*)(v + (size_t)ki * 1024 + d0);
  }

  bf16x8 qf[2][2], kf[2][2];
#pragma unroll
  for (int mf = 0; mf < 2; ++mf)
#pragma unroll
    for (int ks = 0; ks < 2; ++ks){
      qf[mf][ks] = *(const bf16x8*)(q  + (size_t)(mf * 16 + lr) * 1024 + ks * 32 + lk * 8);
      kf[mf][ks] = *(const bf16x8*)(kk + (size_t)(mf * 16 + lr) * 1024 + ks * 32 + lk * 8);
    }

  f32x4 sc[2][2] = {};
#pragma unroll
  for (int mf = 0; mf < 2; ++mf)
#pragma unroll
    for (int nf = 0; nf < 2; ++nf){
      sc[mf][nf] = mfma16(qf[mf][0], kf[nf][0], sc[mf][nf]);
      sc[mf][nf] = mfma16(qf[mf][1], kf[nf][1], sc[mf][nf]);
      sc[mf][nf] *= 0.125f;  // 1/sqrt(64), QK^T only
    }

  f32x4 p[2][4] = {};
#pragma unroll
  for (int nf = 0; nf < 4; ++nf){
    bf16x8 rf0 = *(const bf16x8*)(rel + (nf * 16 + lr) * 64 + lk * 8);
    bf16x8 rf1 = *(const bf16x8*)(rel + (nf * 16 + lr) * 64 + 32 + lk * 8);
#pragma unroll
    for (int mf = 0; mf < 2; ++mf){
      p[mf][nf] = mfma16(qf[mf][0], rf0, p[mf][nf]);
      p[mf][nf] = mfma16(qf[mf][1], rf1, p[mf][nf]);
    }
  }

  // stage V^T (padded stride 40)
#pragma unroll
  for (int j = 0; j < 4; ++j){
    const int e = j * 64 + lane;
    const int ki = e >> 3, d0 = (e & 7) * 8;
#pragma unroll
    for (int i = 0; i < 8; ++i)
      VT[(d0 + i) * 40 + ki] = (u16)vv[j][i];
  }
  // stage P [32][68]
#pragma unroll
  for (int mf = 0; mf < 2; ++mf)
#pragma unroll
    for (int nf = 0; nf < 4; ++nf)
#pragma unroll
      for (int r = 0; r < 4; ++r)
        P[(mf * 16 + lk * 4 + r) * 68 + nf * 16 + lr] = p[mf][nf][r];

  __syncthreads();

  // scores += P[q, q-k+32]
#pragma unroll
  for (int mf = 0; mf < 2; ++mf)
#pragma unroll
    for (int n2 = 0; n2 < 2; ++n2)
#pragma unroll
      for (int r = 0; r < 4; ++r){
        const int qr = mf * 16 + lk * 4 + r;
        const int kc = n2 * 16 + lr;
        sc[mf][n2][r] += P[qr * 68 + (qr - kc + 32)];
      }

  // softmax per row (32 cols spread over 16 lanes x 2 frags)
#pragma unroll
  for (int mf = 0; mf < 2; ++mf)
#pragma unroll
    for (int r = 0; r < 4; ++r){
      float mx = fmaxf(sc[mf][0][r], sc[mf][1][r]);
#pragma unroll
      for (int m2 = 1; m2 < 16; m2 <<= 1) mx = fmaxf(mx, __shfl_xor(mx, m2, 64));
      const float e0 = __expf(sc[mf][0][r] - mx);
      const float e1 = __expf(sc[mf][1][r] - mx);
      float sm = e0 + e1;
#pragma unroll
      for (int m2 = 1; m2 < 16; m2 <<= 1) sm += __shfl_xor(sm, m2, 64);
      const float inv = 1.f / sm;
      sc[mf][0][r] = e0 * inv;
      sc[mf][1][r] = e1 * inv;
    }

#pragma unroll
  for (int mf = 0; mf < 2; ++mf)
#pragma unroll
    for (int n2 = 0; n2 < 2; ++n2)
#pragma unroll
      for (int r = 0; r < 4; ++r)
        AL[(mf * 16 + lk * 4 + r) * 40 + n2 * 16 + lr] = f2bf(sc[mf][n2][r]);

  __syncthreads();

  bf16x8 paf[2];
  paf[0] = *(const bf16x8*)&AL[(lr) * 40 + lk * 8];
  paf[1] = *(const bf16x8*)&AL[(16 + lr) * 40 + lk * 8];

  f32x4 of[2][4] = {};
#pragma unroll
  for (int nf = 0; nf < 4; ++nf){
    bf16x8 vf = *(const bf16x8*)&VT[(nf * 16 + lr) * 40 + lk * 8];
    of[0][nf] = mfma16(paf[0], vf, of[0][nf]);
    of[1][nf] = mfma16(paf[1], vf, of[1][nf]);
  }
#pragma unroll
  for (int mf = 0; mf < 2; ++mf)
#pragma unroll
    for (int nf = 0; nf < 4; ++nf)
#pragma unroll
      for (int r = 0; r < 4; ++r)
        o[(size_t)(mf * 16 + lk * 4 + r) * 1024 + nf * 16 + lr] = f2bf(of[mf][nf][r]);
}

// ---------------- final act MLP helpers ----------------

__global__ void gather_last(const float* __restrict__ x, u16* __restrict__ out){
  const int i = blockIdx.x * 256 + threadIdx.x;   // 512*1024
  const int b = i >> 10, c = i & 1023;
  out[i] = f2bf(x[((size_t)b * 32 + 31) * 1024 + c]);
}

// fuse: 1 relu->bf16, 3 bias->f32
__global__ void small_gemm(const u16* __restrict__ A, const u16* __restrict__ BT,
                           const float* __restrict__ bias, void* __restrict__ out,
                           int M, int N, int K, int fuse){
  const int idx = blockIdx.x * 256 + threadIdx.x;
  if (idx >= M * N) return;
  const int m = idx / N, n = idx - m * N;
  const u16* a  = A  + (size_t)m * K;
  const u16* bt = BT + (size_t)n * K;
  float acc = 0.f;
  for (int k = 0; k < K; k += 8){
    s16x8 av = *(const s16x8*)(a + k);
    s16x8 bv = *(const s16x8*)(bt + k);
#pragma unroll
    for (int i = 0; i < 8; ++i) acc += bf2f((u16)av[i]) * bf2f((u16)bv[i]);
  }
  float v = acc + bias[n];
  if (fuse == 1) v = fmaxf(v, 0.f);
  if (fuse == 3) ((float*)out)[idx] = v;
  else           ((u16*)out)[idx]   = f2bf(v);
}

// ---------------- host ----------------

extern "C" void kernel_launch(void* const* d_in, const int* in_sizes, int n_in,
                              void* d_out, int out_size, void* d_ws, size_t ws_size,
                              hipStream_t stream)
{
  (void)in_sizes; (void)n_in; (void)out_size;
  const float* obs    = (const float*)d_in[0];
  const float* refp   = (const float*)d_in[1];
  const float* obs_w0 = (const float*)d_in[2];
  const float* obs_b0 = (const float*)d_in[3];
  const float* obs_w1 = (const float*)d_in[4];
  const float* obs_b1 = (const float*)d_in[5];
  const float* obs_w2 = (const float*)d_in[6];
  const float* obs_b2 = (const float*)d_in[7];
  const float* ref_w0 = (const float*)d_in[8];
  const float* ref_b0 = (const float*)d_in[9];
  const float* ref_w1 = (const float*)d_in[10];
  const float* ref_b1 = (const float*)d_in[11];
  const float* ref_w2 = (const float*)d_in[12];
  const float* ref_b2 = (const float*)d_in[13];
  const float* pos    = (const float*)d_in[14];
  const float* Wq     = (const float*)d_in[15];
  const float* Wk     = (const float*)d_in[16];
  const float* Wv     = (const float*)d_in[17];
  const float* Wo     = (const float*)d_in[18];
  const float* bo     = (const float*)d_in[19];
  const float* rel    = (const float*)d_in[20];
  const float* ff_w1  = (const float*)d_in[21];
  const float* ff_b1  = (const float*)d_in[22];
  const float* ff_w2  = (const float*)d_in[23];
  const float* ff_b2  = (const float*)d_in[24];
  const float* ln1g   = (const float*)d_in[25];
  const float* ln1b   = (const float*)d_in[26];
  const float* ln2g   = (const float*)d_in[27];
  const float* ln2b   = (const float*)d_in[28];
  const float* act_w0 = (const float*)d_in[29];
  const float* act_b0 = (const float*)d_in[30];
  const float* act_w1 = (const float*)d_in[31];
  const float* act_b1 = (const float*)d_in[32];
  const float* act_w2 = (const float*)d_in[33];
  const float* act_b2 = (const float*)d_in[34];
  float* outp = (float*)d_out;

  char* wsp = (char*)d_ws; size_t off = 0;
  auto alloc = [&](size_t bytes)->char*{ char* p = wsp + off;
                                         off = (off + bytes + 255) & ~(size_t)255; return p; };

  // persistent small weights (~2.4 MB)
  u16* wt_obs0 = (u16*)alloc((size_t)512 * 256 * 2);
  u16* wt_obs1 = (u16*)alloc((size_t)256 * 512 * 2);
  u16* wt_obs2 = (u16*)alloc((size_t)1024 * 256 * 2);
  u16* wt_ref0 = (u16*)alloc((size_t)256 * 128 * 2);
  u16* wt_ref1 = (u16*)alloc((size_t)256 * 256 * 2);
  u16* wt_ref2 = (u16*)alloc((size_t)1024 * 256 * 2);
  u16* wt_a0   = (u16*)alloc((size_t)256 * 1024 * 2);
  u16* wt_a1   = (u16*)alloc((size_t)128 * 256 * 2);
  u16* wt_a2   = (u16*)alloc((size_t)32 * 128 * 2);
  u16* rel_bf  = (u16*)alloc((size_t)6 * 65 * 64 * 2);
  // per-layer weight buffer (16 MB, reused each layer)
  u16* wt_lq   = (u16*)alloc((size_t)1024 * 1024 * 2);
  u16* wt_lk   = (u16*)alloc((size_t)1024 * 1024 * 2);
  u16* wt_lv   = (u16*)alloc((size_t)1024 * 1024 * 2);
  u16* wt_lo   = (u16*)alloc((size_t)1024 * 1024 * 2);
  u16* wt_lf1  = (u16*)alloc((size_t)2048 * 1024 * 2);
  u16* wt_lf2  = (u16*)alloc((size_t)2048 * 1024 * 2);
  // activations
  float* x     = (float*)alloc((size_t)16384 * 1024 * 4);   // 67 MB, fp32 residual
  u16* xn      = (u16*)alloc((size_t)16384 * 1024 * 2);     // 33.5 MB
  u16* qb      = (u16*)alloc((size_t)16384 * 1024 * 2);
  u16* kb      = (u16*)alloc((size_t)16384 * 1024 * 2);
  u16* vb      = (u16*)alloc((size_t)16384 * 1024 * 2);

  if (off > ws_size) return;  // clean diagnostic failure instead of a GPU fault

  // aliases (stream-order-safe):
  u16* obs_bf = qb;   // embed phase only
  u16* h1     = kb;
  u16* h2     = vb;
  u16* ref_bf = xn;
  u16* ob     = xn;   // attn out: xn dead after q/k/v GEMMs
  u16* ffb    = qb;   // ff hidden [16384,2048] spans qb+kb, both dead during FF
  u16* xlast  = qb;   // after last layer
  u16* a1b    = kb;
  u16* a2b    = vb;

  auto CV = [&](const float* src, u16* dst, int n){
    cvt_bf16<<<dim3((n / 4 + 255) / 256), dim3(256), 0, stream>>>(src, dst, n);
  };
  auto TR = [&](const float* W, u16* WT, int Kd, int Nd, int nz){
    trans_w<<<dim3(Nd / 32, Kd / 32, nz), dim3(32, 8), 0, stream>>>(W, WT, Kd, Nd);
  };
  auto GM = [&](const u16* A, const u16* BT, const float* bias, const float* resid,
                const float* posb, void* op, int Md, int Nd, int Kd, int fuse){
    gemm128<<<dim3(Nd / 128, Md / 128), dim3(256), 0, stream>>>(A, BT, bias, resid, posb, op, Md, Nd, Kd, fuse);
  };

  // small weight prep
  CV(rel, rel_bf, 6 * 65 * 64);
  TR(obs_w0, wt_obs0, 256, 512, 1);
  TR(obs_w1, wt_obs1, 512, 256, 1);
  TR(obs_w2, wt_obs2, 256, 1024, 1);
  TR(ref_w0, wt_ref0, 128, 256, 1);
  TR(ref_w1, wt_ref1, 256, 256, 1);
  TR(ref_w2, wt_ref2, 256, 1024, 1);
  TR(act_w0, wt_a0, 1024, 256, 1);
  TR(act_w1, wt_a1, 256, 128, 1);
  TR(act_w2, wt_a2, 128, 32, 1);

  const int M = 16384;
  // embed: x = mlp3(obs) + mlp3(ref) + pos
  CV(obs, obs_bf, 16384 * 256);                      // obs_bf = qb
  GM(obs_bf, wt_obs0, obs_b0, nullptr, nullptr, h1, M, 512, 256, 1);   // h1 = kb
  GM(h1,     wt_obs1, obs_b1, nullptr, nullptr, h2, M, 256, 512, 1);   // h2 = vb
  GM(h2,     wt_obs2, obs_b2, nullptr, nullptr, x,  M, 1024, 256, 3);
  CV(refp, ref_bf, 16384 * 128);                     // ref_bf = xn
  GM(ref_bf, wt_ref0, ref_b0, nullptr, nullptr, h2, M, 256, 128, 1);
  GM(h2,     wt_ref1, ref_b1, nullptr, nullptr, h1, M, 256, 256, 1);
  GM(h1,     wt_ref2, ref_b2, x, pos,           x,  M, 1024, 256, 5);

  for (int l = 0; l < 6; ++l){
    // per-layer weight conversion into the shared 16MB buffer
    TR(Wq + (size_t)l * 1048576, wt_lq, 1024, 1024, 1);
    TR(Wk + (size_t)l * 1048576, wt_lk, 1024, 1024, 1);
    TR(Wv + (size_t)l * 1048576, wt_lv, 1024, 1024, 1);
    TR(Wo + (size_t)l * 1048576, wt_lo, 1024, 1024, 1);
    TR(ff_w1 + (size_t)l * 2097152, wt_lf1, 1024, 2048, 1);
    TR(ff_w2 + (size_t)l * 2097152, wt_lf2, 2048, 1024, 1);

    ln_k<<<dim3(16384), dim3(256), 0, stream>>>(x, ln1g + l * 1024, ln1b + l * 1024, xn);
    GM(xn, wt_lq, nullptr, nullptr, nullptr, qb, M, 1024, 1024, 0);
    GM(xn, wt_lk, nullptr, nullptr, nullptr, kb, M, 1024, 1024, 0);
    GM(xn, wt_lv, nullptr, nullptr, nullptr, vb, M, 1024, 1024, 0);
    attn_k<<<dim3(2048), dim3(256), 0, stream>>>(qb, kb, vb, rel_bf + (size_t)l * 4160, ob);
    GM(ob, wt_lo, bo + l * 1024, x, nullptr, x, M, 1024, 1024, 4);
    ln_k<<<dim3(16384), dim3(256), 0, stream>>>(x, ln2g + l * 1024, ln2b + l * 1024, xn);
    GM(xn,  wt_lf1, ff_b1 + l * 2048, nullptr, nullptr, ffb, M, 2048, 1024, 2);
    GM(ffb, wt_lf2, ff_b2 + l * 1024, x, nullptr, x, M, 1024, 2048, 4);
  }

  gather_last<<<dim3(2048), dim3(256), 0, stream>>>(x, xlast);
  small_gemm<<<dim3(512 * 256 / 256), dim3(256), 0, stream>>>(xlast, wt_a0, act_b0, a1b, 512, 256, 1024, 1);
  small_gemm<<<dim3(512 * 128 / 256), dim3(256), 0, stream>>>(a1b, wt_a1, act_b1, a2b, 512, 128, 256, 1);
  small_gemm<<<dim3(512 * 32 / 256),  dim3(256), 0, stream>>>(a2b, wt_a2, act_b2, outp, 512, 32, 128, 3);
}

// Round 3
// 3980.510 us; speedup vs baseline: 1.1331x; 1.1331x over previous
//
#include <hip/hip_runtime.h>
#include <cstdint>
#include <cstddef>

typedef unsigned short u16;
typedef float f32x4 __attribute__((ext_vector_type(4)));
typedef short s16x8 __attribute__((ext_vector_type(8)));
typedef __bf16 bf16x8 __attribute__((ext_vector_type(8)));

#define DEVINL __device__ __forceinline__

DEVINL float bf2f(u16 u){ union{unsigned int i; float f;} c; c.i=((unsigned int)u)<<16; return c.f; }
DEVINL u16 f2bf(float f){ union{float f; unsigned int i;} c; c.f=f; unsigned int u=c.i;
                          u += 0x7FFF + ((u>>16)&1); return (u16)(u>>16); }

DEVINL f32x4 mfma16(bf16x8 a, bf16x8 b, f32x4 c){
  return __builtin_amdgcn_mfma_f32_16x16x32_bf16(a, b, c, 0, 0, 0);
}

typedef const __attribute__((address_space(1))) void* gas1p;
typedef __attribute__((address_space(3))) void* as3p;
DEVINL void async16(const void* g, void* l){
  __builtin_amdgcn_global_load_lds((gas1p)g, (as3p)l, 16, 0, 0);
}

// ---------------- weight prep ----------------

__global__ void cvt_bf16(const float* __restrict__ in, u16* __restrict__ out, int n){
  int i = (blockIdx.x * 256 + threadIdx.x) * 4;
  if (i >= n) return;
  float4 v = *(const float4*)(in + i);
  short4 sv = make_short4((short)f2bf(v.x), (short)f2bf(v.y), (short)f2bf(v.z), (short)f2bf(v.w));
  *(short4*)(out + i) = sv;
}

// W [K][N] f32  ->  WT [N][K] bf16   (grid: (N/32, K/32, nmat), block (32,8))
__global__ __launch_bounds__(256) void trans_w(const float* __restrict__ W, u16* __restrict__ WT,
                                               int K, int N){
  __shared__ float t[32][33];
  const float* Wm = W  + (size_t)blockIdx.z * K * N;
  u16*         Tm = WT + (size_t)blockIdx.z * K * N;
  const int x = threadIdx.x, y = threadIdx.y;
  const int n0 = blockIdx.x * 32, k0 = blockIdx.y * 32;
#pragma unroll
  for (int j = 0; j < 32; j += 8)
    t[y + j][x] = Wm[(size_t)(k0 + y + j) * N + n0 + x];
  __syncthreads();
#pragma unroll
  for (int j = 0; j < 32; j += 8)
    Tm[(size_t)(n0 + y + j) * K + k0 + x] = f2bf(t[x][y + j]);
}

// ---------------- main GEMM: C[M,N] = A[M,K](bf16) * BT[N,K](bf16)^T ----------------
// fuse: 0 bias->bf16, 1 relu->bf16, 2 gelu->bf16, 3 bias->f32, 4 resid+bias->f32,
//       5 resid+bias+pos->f32 (N must be 1024)

__global__ __launch_bounds__(256) void gemm128(
    const u16* __restrict__ A, const u16* __restrict__ BT,
    const float* __restrict__ bias, const float* __restrict__ resid,
    const float* __restrict__ pos, void* __restrict__ out,
    int M, int N, int K, int fuse)
{
  __shared__ u16 As[2][4096];
  __shared__ u16 Bs[2][4096];
  const int tid = threadIdx.x;

  // T1: bijective XCD-chunked swizzle (m204). Consecutive logical blocks
  // (bn fastest within one bm panel) land on the SAME XCD -> A-panel stays
  // L2-resident across its bn sweep; B panel becomes XCD-L2/L3 resident.
  const int nbn = gridDim.x;
  const int nwg = gridDim.x * gridDim.y;
  const int lid = blockIdx.y * nbn + blockIdx.x;
  const int q8 = nwg >> 3, r8 = nwg & 7;
  const int xcd = lid & 7, posi = lid >> 3;
  const int swz = (xcd < r8 ? xcd * (q8 + 1) : r8 * (q8 + 1) + (xcd - r8) * q8) + posi;
  const int bm = swz / nbn, bn = swz - bm * nbn;

  const int lane = tid & 63, wid = tid >> 6;
  const int lr = lane & 15, lk = lane >> 4;
  const int wm = (wid >> 1) * 64, wn = (wid & 1) * 64;

  f32x4 acc[4][4] = {};

  const int r0 = tid >> 2;
  const int c0 = (tid & 3) * 8;
  const u16* Ab = A  + (size_t)(bm * 128 + r0) * K + c0;
  const u16* Bb = BT + (size_t)(bn * 128 + r0) * K + c0;
  const size_t rstep = (size_t)64 * K;
  const int nk = K >> 5;

  async16(Ab,         &As[0][tid * 8]);
  async16(Ab + rstep, &As[0][2048 + tid * 8]);
  async16(Bb,         &Bs[0][tid * 8]);
  async16(Bb + rstep, &Bs[0][2048 + tid * 8]);

  int cur = 0;
  for (int kt = 0; kt < nk; ++kt){
    __syncthreads();
    if (kt + 1 < nk){
      const u16* An = Ab + (size_t)(kt + 1) * 32;
      const u16* Bn = Bb + (size_t)(kt + 1) * 32;
      u16* Asn = &As[cur ^ 1][0];
      u16* Bsn = &Bs[cur ^ 1][0];
      async16(An,         Asn + tid * 8);
      async16(An + rstep, Asn + 2048 + tid * 8);
      async16(Bn,         Bsn + tid * 8);
      async16(Bn + rstep, Bsn + 2048 + tid * 8);
    }
    bf16x8 af[4], bfv[4];
#pragma unroll
    for (int i = 0; i < 4; ++i)
      af[i] = *(const bf16x8*)&As[cur][(wm + i * 16 + lr) * 32 + lk * 8];
#pragma unroll
    for (int j = 0; j < 4; ++j)
      bfv[j] = *(const bf16x8*)&Bs[cur][(wn + j * 16 + lr) * 32 + lk * 8];
#pragma unroll
    for (int i = 0; i < 4; ++i)
#pragma unroll
      for (int j = 0; j < 4; ++j)
        acc[i][j] = mfma16(af[i], bfv[j], acc[i][j]);
    cur ^= 1;
  }

  const int gm0 = bm * 128 + wm, gn0 = bn * 128 + wn;
  float* outf = (float*)out;
  u16*   outb = (u16*)out;
#pragma unroll
  for (int i = 0; i < 4; ++i){
#pragma unroll
    for (int j = 0; j < 4; ++j){
      const int col = gn0 + j * 16 + lr;
      const float bv = bias ? bias[col] : 0.f;
#pragma unroll
      for (int r = 0; r < 4; ++r){
        const int row = gm0 + i * 16 + lk * 4 + r;
        const size_t idx = (size_t)row * N + col;
        float v = acc[i][j][r] + bv;
        if (fuse == 1)      v = fmaxf(v, 0.f);
        else if (fuse == 2) v = 0.5f * v * (1.f + erff(v * 0.70710678118654752f));
        else if (fuse == 4) v += resid[idx];
        else if (fuse == 5) v += resid[idx] + pos[((row & 31) << 10) + col];
        if (fuse >= 3) outf[idx] = v;
        else           outb[idx] = f2bf(v);
      }
    }
  }
}

// ---------------- LayerNorm: fp32 in -> bf16 out ----------------

__global__ __launch_bounds__(256) void ln_k(
    const float* __restrict__ x, const float* __restrict__ g,
    const float* __restrict__ b, u16* __restrict__ out)
{
  const int row = blockIdx.x;
  const float* xr = x + (size_t)row * 1024;
  const int tid = threadIdx.x;
  float4 v = *(const float4*)(xr + tid * 4);
  float s  = v.x + v.y + v.z + v.w;
  float ss = v.x * v.x + v.y * v.y + v.z * v.z + v.w * v.w;
#pragma unroll
  for (int m = 1; m < 64; m <<= 1){ s += __shfl_xor(s, m, 64); ss += __shfl_xor(ss, m, 64); }
  __shared__ float red[8];
  if ((tid & 63) == 0){ red[tid >> 6] = s; red[4 + (tid >> 6)] = ss; }
  __syncthreads();
  s  = red[0] + red[1] + red[2] + red[3];
  ss = red[4] + red[5] + red[6] + red[7];
  const float mu = s * (1.f / 1024.f);
  const float rs = rsqrtf(ss * (1.f / 1024.f) - mu * mu + 1e-5f);
  float4 gg = *(const float4*)(g + tid * 4);
  float4 bb = *(const float4*)(b + tid * 4);
  short4 sv = make_short4((short)f2bf((v.x - mu) * rs * gg.x + bb.x),
                          (short)f2bf((v.y - mu) * rs * gg.y + bb.y),
                          (short)f2bf((v.z - mu) * rs * gg.z + bb.z),
                          (short)f2bf((v.w - mu) * rs * gg.w + bb.w));
  *(short4*)(out + (size_t)row * 1024 + tid * 4) = sv;
}

// ---------------- attention: one wave per (b,h), S=32, HD=64 ----------------
// QKV packed: row stride 3072; q at col h*64, k at +1024, v at +2048.

__global__ __launch_bounds__(256) void attn_k(
    const u16* __restrict__ QKV, const u16* __restrict__ rel,
    u16* __restrict__ O)
{
  __shared__ char smem[65536];
  const int tid = threadIdx.x;
  const int wid = tid >> 6, lane = tid & 63;
  const int lr = lane & 15, lk = lane >> 4;
  char* sw = smem + wid * 16384;
  float* P = (float*)sw;            // [32][68] f32
  u16*  AL = (u16*)(sw + 8704);     // [32][40] bf16 (attn probs)
  u16*  VT = (u16*)(sw + 11264);    // [64][40] bf16 (V^T)

  const int pair = blockIdx.x * 4 + wid;
  const int b = pair >> 4, h = pair & 15;
  const u16* q  = QKV + (size_t)b * 32 * 3072 + (size_t)h * 64;
  const u16* kk = q + 1024;
  const u16* v  = q + 2048;
  u16* o = O + (size_t)b * 32768 + (size_t)h * 64;

  s16x8 vv[4];
#pragma unroll
  for (int j = 0; j < 4; ++j){
    const int e = j * 64 + lane;
    const int ki = e >> 3, d0 = (e & 7) * 8;
    vv[j] = *(const s16x8*)(v + (size_t)ki * 3072 + d0);
  }

  bf16x8 qf[2][2], kf[2][2];
#pragma unroll
  for (int mf = 0; mf < 2; ++mf)
#pragma unroll
    for (int ks = 0; ks < 2; ++ks){
      qf[mf][ks] = *(const bf16x8*)(q  + (size_t)(mf * 16 + lr) * 3072 + ks * 32 + lk * 8);
      kf[mf][ks] = *(const bf16x8*)(kk + (size_t)(mf * 16 + lr) * 3072 + ks * 32 + lk * 8);
    }

  f32x4 sc[2][2] = {};
#pragma unroll
  for (int mf = 0; mf < 2; ++mf)
#pragma unroll
    for (int nf = 0; nf < 2; ++nf){
      sc[mf][nf] = mfma16(qf[mf][0], kf[nf][0], sc[mf][nf]);
      sc[mf][nf] = mfma16(qf[mf][1], kf[nf][1], sc[mf][nf]);
      sc[mf][nf] *= 0.125f;  // 1/sqrt(64), QK^T only
    }

  f32x4 p[2][4] = {};
#pragma unroll
  for (int nf = 0; nf < 4; ++nf){
    bf16x8 rf0 = *(const bf16x8*)(rel + (nf * 16 + lr) * 64 + lk * 8);
    bf16x8 rf1 = *(const bf16x8*)(rel + (nf * 16 + lr) * 64 + 32 + lk * 8);
#pragma unroll
    for (int mf = 0; mf < 2; ++mf){
      p[mf][nf] = mfma16(qf[mf][0], rf0, p[mf][nf]);
      p[mf][nf] = mfma16(qf[mf][1], rf1, p[mf][nf]);
    }
  }

  // stage V^T (padded stride 40)
#pragma unroll
  for (int j = 0; j < 4; ++j){
    const int e = j * 64 + lane;
    const int ki = e >> 3, d0 = (e & 7) * 8;
#pragma unroll
    for (int i = 0; i < 8; ++i)
      VT[(d0 + i) * 40 + ki] = (u16)vv[j][i];
  }
  // stage P [32][68]
#pragma unroll
  for (int mf = 0; mf < 2; ++mf)
#pragma unroll
    for (int nf = 0; nf < 4; ++nf)
#pragma unroll
      for (int r = 0; r < 4; ++r)
        P[(mf * 16 + lk * 4 + r) * 68 + nf * 16 + lr] = p[mf][nf][r];

  __syncthreads();

  // scores += P[q, q-k+32]
#pragma unroll
  for (int mf = 0; mf < 2; ++mf)
#pragma unroll
    for (int n2 = 0; n2 < 2; ++n2)
#pragma unroll
      for (int r = 0; r < 4; ++r){
        const int qr = mf * 16 + lk * 4 + r;
        const int kc = n2 * 16 + lr;
        sc[mf][n2][r] += P[qr * 68 + (qr - kc + 32)];
      }

  // softmax per row (32 cols spread over 16 lanes x 2 frags)
#pragma unroll
  for (int mf = 0; mf < 2; ++mf)
#pragma unroll
    for (int r = 0; r < 4; ++r){
      float mx = fmaxf(sc[mf][0][r], sc[mf][1][r]);
#pragma unroll
      for (int m2 = 1; m2 < 16; m2 <<= 1) mx = fmaxf(mx, __shfl_xor(mx, m2, 64));
      const float e0 = __expf(sc[mf][0][r] - mx);
      const float e1 = __expf(sc[mf][1][r] - mx);
      float sm = e0 + e1;
#pragma unroll
      for (int m2 = 1; m2 < 16; m2 <<= 1) sm += __shfl_xor(sm, m2, 64);
      const float inv = 1.f / sm;
      sc[mf][0][r] = e0 * inv;
      sc[mf][1][r] = e1 * inv;
    }

#pragma unroll
  for (int mf = 0; mf < 2; ++mf)
#pragma unroll
    for (int n2 = 0; n2 < 2; ++n2)
#pragma unroll
      for (int r = 0; r < 4; ++r)
        AL[(mf * 16 + lk * 4 + r) * 40 + n2 * 16 + lr] = f2bf(sc[mf][n2][r]);

  __syncthreads();

  bf16x8 paf[2];
  paf[0] = *(const bf16x8*)&AL[(lr) * 40 + lk * 8];
  paf[1] = *(const bf16x8*)&AL[(16 + lr) * 40 + lk * 8];

  f32x4 of[2][4] = {};
#pragma unroll
  for (int nf = 0; nf < 4; ++nf){
    bf16x8 vf = *(const bf16x8*)&VT[(nf * 16 + lr) * 40 + lk * 8];
    of[0][nf] = mfma16(paf[0], vf, of[0][nf]);
    of[1][nf] = mfma16(paf[1], vf, of[1][nf]);
  }
#pragma unroll
  for (int mf = 0; mf < 2; ++mf)
#pragma unroll
    for (int nf = 0; nf < 4; ++nf)
#pragma unroll
      for (int r = 0; r < 4; ++r)
        o[(size_t)(mf * 16 + lk * 4 + r) * 1024 + nf * 16 + lr] = f2bf(of[mf][nf][r]);
}

// ---------------- final act MLP helpers ----------------

__global__ void gather_last(const float* __restrict__ x, u16* __restrict__ out){
  const int i = blockIdx.x * 256 + threadIdx.x;   // 512*1024
  const int b = i >> 10, c = i & 1023;
  out[i] = f2bf(x[((size_t)b * 32 + 31) * 1024 + c]);
}

// fuse: 1 relu->bf16, 3 bias->f32
__global__ void small_gemm(const u16* __restrict__ A, const u16* __restrict__ BT,
                           const float* __restrict__ bias, void* __restrict__ out,
                           int M, int N, int K, int fuse){
  const int idx = blockIdx.x * 256 + threadIdx.x;
  if (idx >= M * N) return;
  const int m = idx / N, n = idx - m * N;
  const u16* a  = A  + (size_t)m * K;
  const u16* bt = BT + (size_t)n * K;
  float acc = 0.f;
  for (int k = 0; k < K; k += 8){
    s16x8 av = *(const s16x8*)(a + k);
    s16x8 bv = *(const s16x8*)(bt + k);
#pragma unroll
    for (int i = 0; i < 8; ++i) acc += bf2f((u16)av[i]) * bf2f((u16)bv[i]);
  }
  float v = acc + bias[n];
  if (fuse == 1) v = fmaxf(v, 0.f);
  if (fuse == 3) ((float*)out)[idx] = v;
  else           ((u16*)out)[idx]   = f2bf(v);
}

// ---------------- host ----------------

extern "C" void kernel_launch(void* const* d_in, const int* in_sizes, int n_in,
                              void* d_out, int out_size, void* d_ws, size_t ws_size,
                              hipStream_t stream)
{
  (void)in_sizes; (void)n_in; (void)out_size;
  const float* obs    = (const float*)d_in[0];
  const float* refp   = (const float*)d_in[1];
  const float* obs_w0 = (const float*)d_in[2];
  const float* obs_b0 = (const float*)d_in[3];
  const float* obs_w1 = (const float*)d_in[4];
  const float* obs_b1 = (const float*)d_in[5];
  const float* obs_w2 = (const float*)d_in[6];
  const float* obs_b2 = (const float*)d_in[7];
  const float* ref_w0 = (const float*)d_in[8];
  const float* ref_b0 = (const float*)d_in[9];
  const float* ref_w1 = (const float*)d_in[10];
  const float* ref_b1 = (const float*)d_in[11];
  const float* ref_w2 = (const float*)d_in[12];
  const float* ref_b2 = (const float*)d_in[13];
  const float* pos    = (const float*)d_in[14];
  const float* Wq     = (const float*)d_in[15];
  const float* Wk     = (const float*)d_in[16];
  const float* Wv     = (const float*)d_in[17];
  const float* Wo     = (const float*)d_in[18];
  const float* bo     = (const float*)d_in[19];
  const float* rel    = (const float*)d_in[20];
  const float* ff_w1  = (const float*)d_in[21];
  const float* ff_b1  = (const float*)d_in[22];
  const float* ff_w2  = (const float*)d_in[23];
  const float* ff_b2  = (const float*)d_in[24];
  const float* ln1g   = (const float*)d_in[25];
  const float* ln1b   = (const float*)d_in[26];
  const float* ln2g   = (const float*)d_in[27];
  const float* ln2b   = (const float*)d_in[28];
  const float* act_w0 = (const float*)d_in[29];
  const float* act_b0 = (const float*)d_in[30];
  const float* act_w1 = (const float*)d_in[31];
  const float* act_b1 = (const float*)d_in[32];
  const float* act_w2 = (const float*)d_in[33];
  const float* act_b2 = (const float*)d_in[34];
  float* outp = (float*)d_out;

  char* wsp = (char*)d_ws; size_t off = 0;
  auto alloc = [&](size_t bytes)->char*{ char* p = wsp + off;
                                         off = (off + bytes + 255) & ~(size_t)255; return p; };

  // persistent small weights (~2.4 MB)
  u16* wt_obs0 = (u16*)alloc((size_t)512 * 256 * 2);
  u16* wt_obs1 = (u16*)alloc((size_t)256 * 512 * 2);
  u16* wt_obs2 = (u16*)alloc((size_t)1024 * 256 * 2);
  u16* wt_ref0 = (u16*)alloc((size_t)256 * 128 * 2);
  u16* wt_ref1 = (u16*)alloc((size_t)256 * 256 * 2);
  u16* wt_ref2 = (u16*)alloc((size_t)1024 * 256 * 2);
  u16* wt_a0   = (u16*)alloc((size_t)256 * 1024 * 2);
  u16* wt_a1   = (u16*)alloc((size_t)128 * 256 * 2);
  u16* wt_a2   = (u16*)alloc((size_t)32 * 128 * 2);
  u16* rel_bf  = (u16*)alloc((size_t)6 * 65 * 64 * 2);
  // per-layer weight buffers (16 MB, reused each layer)
  u16* wt_qkv  = (u16*)alloc((size_t)3072 * 1024 * 2);   // rows: [Wq^T; Wk^T; Wv^T]
  u16* wt_lo   = (u16*)alloc((size_t)1024 * 1024 * 2);
  u16* wt_lf1  = (u16*)alloc((size_t)2048 * 1024 * 2);
  u16* wt_lf2  = (u16*)alloc((size_t)2048 * 1024 * 2);
  // activations
  float* x     = (float*)alloc((size_t)16384 * 1024 * 4);   // 67 MB, fp32 residual
  u16* xn      = (u16*)alloc((size_t)16384 * 1024 * 2);     // 33.5 MB
  u16* qkv     = (u16*)alloc((size_t)16384 * 3072 * 2);     // 100.7 MB

  if (off > ws_size) return;  // clean diagnostic failure instead of a GPU fault

  // aliases (stream-order-safe):
  u16* obs_bf = qkv;                              // embed phase only
  u16* h1     = qkv + (size_t)16384 * 256;        // [16384,512]
  u16* h2     = qkv + (size_t)16384 * 768;        // [16384,256]
  u16* ref_bf = xn;
  u16* ob     = xn;                               // attn out: xn dead after qkv GEMM
  u16* ffb    = qkv;                              // ff hidden [16384,2048], qkv dead during FF
  u16* xlast  = qkv;                              // after last layer
  u16* a1b    = qkv + (size_t)16384 * 256;
  u16* a2b    = qkv + (size_t)16384 * 512;

  auto CV = [&](const float* src, u16* dst, int n){
    cvt_bf16<<<dim3((n / 4 + 255) / 256), dim3(256), 0, stream>>>(src, dst, n);
  };
  auto TR = [&](const float* W, u16* WT, int Kd, int Nd, int nz){
    trans_w<<<dim3(Nd / 32, Kd / 32, nz), dim3(32, 8), 0, stream>>>(W, WT, Kd, Nd);
  };
  auto GM = [&](const u16* A, const u16* BT, const float* bias, const float* resid,
                const float* posb, void* op, int Md, int Nd, int Kd, int fuse){
    gemm128<<<dim3(Nd / 128, Md / 128), dim3(256), 0, stream>>>(A, BT, bias, resid, posb, op, Md, Nd, Kd, fuse);
  };

  // small weight prep
  CV(rel, rel_bf, 6 * 65 * 64);
  TR(obs_w0, wt_obs0, 256, 512, 1);
  TR(obs_w1, wt_obs1, 512, 256, 1);
  TR(obs_w2, wt_obs2, 256, 1024, 1);
  TR(ref_w0, wt_ref0, 128, 256, 1);
  TR(ref_w1, wt_ref1, 256, 256, 1);
  TR(ref_w2, wt_ref2, 256, 1024, 1);
  TR(act_w0, wt_a0, 1024, 256, 1);
  TR(act_w1, wt_a1, 256, 128, 1);
  TR(act_w2, wt_a2, 128, 32, 1);

  const int M = 16384;
  // embed: x = mlp3(obs) + mlp3(ref) + pos
  CV(obs, obs_bf, 16384 * 256);
  GM(obs_bf, wt_obs0, obs_b0, nullptr, nullptr, h1, M, 512, 256, 1);
  GM(h1,     wt_obs1, obs_b1, nullptr, nullptr, h2, M, 256, 512, 1);
  GM(h2,     wt_obs2, obs_b2, nullptr, nullptr, x,  M, 1024, 256, 3);
  CV(refp, ref_bf, 16384 * 128);
  GM(ref_bf, wt_ref0, ref_b0, nullptr, nullptr, h2, M, 256, 128, 1);
  GM(h2,     wt_ref1, ref_b1, nullptr, nullptr, h1, M, 256, 256, 1);
  GM(h1,     wt_ref2, ref_b2, x, pos,           x,  M, 1024, 256, 5);

  for (int l = 0; l < 6; ++l){
    // per-layer weight conversion into the shared buffers
    TR(Wq + (size_t)l * 1048576, wt_qkv,                        1024, 1024, 1);
    TR(Wk + (size_t)l * 1048576, wt_qkv + (size_t)1024 * 1024,  1024, 1024, 1);
    TR(Wv + (size_t)l * 1048576, wt_qkv + (size_t)2048 * 1024,  1024, 1024, 1);
    TR(Wo + (size_t)l * 1048576, wt_lo, 1024, 1024, 1);
    TR(ff_w1 + (size_t)l * 2097152, wt_lf1, 1024, 2048, 1);
    TR(ff_w2 + (size_t)l * 2097152, wt_lf2, 2048, 1024, 1);

    ln_k<<<dim3(16384), dim3(256), 0, stream>>>(x, ln1g + l * 1024, ln1b + l * 1024, xn);
    GM(xn, wt_qkv, nullptr, nullptr, nullptr, qkv, M, 3072, 1024, 0);
    attn_k<<<dim3(2048), dim3(256), 0, stream>>>(qkv, rel_bf + (size_t)l * 4160, ob);
    GM(ob, wt_lo, bo + l * 1024, x, nullptr, x, M, 1024, 1024, 4);
    ln_k<<<dim3(16384), dim3(256), 0, stream>>>(x, ln2g + l * 1024, ln2b + l * 1024, xn);
    GM(xn,  wt_lf1, ff_b1 + l * 2048, nullptr, nullptr, ffb, M, 2048, 1024, 2);
    GM(ffb, wt_lf2, ff_b2 + l * 1024, x, nullptr, x, M, 1024, 2048, 4);
  }

  gather_last<<<dim3(2048), dim3(256), 0, stream>>>(x, xlast);
  small_gemm<<<dim3(512 * 256 / 256), dim3(256), 0, stream>>>(xlast, wt_a0, act_b0, a1b, 512, 256, 1024, 1);
  small_gemm<<<dim3(512 * 128 / 256), dim3(256), 0, stream>>>(a1b, wt_a1, act_b1, a2b, 512, 128, 256, 1);
  small_gemm<<<dim3(512 * 32 / 256),  dim3(256), 0, stream>>>(a2b, wt_a2, act_b2, outp, 512, 32, 128, 3);
}

// Round 5
// 3783.743 us; speedup vs baseline: 1.1920x; 1.0520x over previous
//
#include <hip/hip_runtime.h>
#include <cstdint>
#include <cstddef>

typedef unsigned short u16;
typedef float f32x4 __attribute__((ext_vector_type(4)));
typedef short s16x8 __attribute__((ext_vector_type(8)));
typedef __bf16 bf16x8 __attribute__((ext_vector_type(8)));

#define DEVINL __device__ __forceinline__

DEVINL float bf2f(u16 u){ union{unsigned int i; float f;} c; c.i=((unsigned int)u)<<16; return c.f; }
DEVINL u16 f2bf(float f){ union{float f; unsigned int i;} c; c.f=f; unsigned int u=c.i;
                          u += 0x7FFF + ((u>>16)&1); return (u16)(u>>16); }

DEVINL f32x4 mfma16(bf16x8 a, bf16x8 b, f32x4 c){
  return __builtin_amdgcn_mfma_f32_16x16x32_bf16(a, b, c, 0, 0, 0);
}

typedef const __attribute__((address_space(1))) void* gas1p;
typedef __attribute__((address_space(3))) void* as3p;
DEVINL void async16(const void* g, void* l){
  __builtin_amdgcn_global_load_lds((gas1p)g, (as3p)l, 16, 0, 0);
}

// st_16x32 LDS swizzle (m201): XOR byte-bit-5 with byte-bit-9, involution.
#define SWZ(b) ((b) ^ ((((b) >> 9) & 1) << 5))

// ---------------- weight prep ----------------

__global__ void cvt_bf16(const float* __restrict__ in, u16* __restrict__ out, int n){
  int i = (blockIdx.x * 256 + threadIdx.x) * 4;
  if (i >= n) return;
  float4 v = *(const float4*)(in + i);
  short4 sv = make_short4((short)f2bf(v.x), (short)f2bf(v.y), (short)f2bf(v.z), (short)f2bf(v.w));
  *(short4*)(out + i) = sv;
}

// W [K][N] f32  ->  WT [N][K] bf16   (grid: (N/32, K/32, nmat), block (32,8))
__global__ __launch_bounds__(256) void trans_w(const float* __restrict__ W, u16* __restrict__ WT,
                                               int K, int N){
  __shared__ float t[32][33];
  const float* Wm = W  + (size_t)blockIdx.z * K * N;
  u16*         Tm = WT + (size_t)blockIdx.z * K * N;
  const int x = threadIdx.x, y = threadIdx.y;
  const int n0 = blockIdx.x * 32, k0 = blockIdx.y * 32;
#pragma unroll
  for (int j = 0; j < 32; j += 8)
    t[y + j][x] = Wm[(size_t)(k0 + y + j) * N + n0 + x];
  __syncthreads();
#pragma unroll
  for (int j = 0; j < 32; j += 8)
    Tm[(size_t)(n0 + y + j) * K + k0 + x] = f2bf(t[x][y + j]);
}

// ---------------- small GEMM (embed MLPs): 128x128 tile, m97 structure ----------------
// fuse: 0 bias->bf16, 1 relu->bf16, 2 gelu->bf16, 3 bias->f32, 4 resid+bias->f32,
//       5 resid+bias+pos->f32 (N must be 1024)

__global__ __launch_bounds__(256) void gemm128(
    const u16* __restrict__ A, const u16* __restrict__ BT,
    const float* __restrict__ bias, const float* __restrict__ resid,
    const float* __restrict__ pos, void* __restrict__ out,
    int M, int N, int K, int fuse)
{
  __shared__ u16 As[2][4096];
  __shared__ u16 Bs[2][4096];
  const int tid = threadIdx.x;

  const int nbn = gridDim.x;
  const int nwg = gridDim.x * gridDim.y;
  const int lid = blockIdx.y * nbn + blockIdx.x;
  const int q8 = nwg >> 3, r8 = nwg & 7;
  const int xcd = lid & 7, posi = lid >> 3;
  const int swz = (xcd < r8 ? xcd * (q8 + 1) : r8 * (q8 + 1) + (xcd - r8) * q8) + posi;
  const int bm = swz / nbn, bn = swz - bm * nbn;

  const int lane = tid & 63, wid = tid >> 6;
  const int lr = lane & 15, lk = lane >> 4;
  const int wm = (wid >> 1) * 64, wn = (wid & 1) * 64;

  f32x4 acc[4][4] = {};

  const int r0 = tid >> 2;
  const int c0 = (tid & 3) * 8;
  const u16* Ab = A  + (size_t)(bm * 128 + r0) * K + c0;
  const u16* Bb = BT + (size_t)(bn * 128 + r0) * K + c0;
  const size_t rstep = (size_t)64 * K;
  const int nk = K >> 5;

  async16(Ab,         &As[0][tid * 8]);
  async16(Ab + rstep, &As[0][2048 + tid * 8]);
  async16(Bb,         &Bs[0][tid * 8]);
  async16(Bb + rstep, &Bs[0][2048 + tid * 8]);

  int cur = 0;
  for (int kt = 0; kt < nk; ++kt){
    __syncthreads();
    if (kt + 1 < nk){
      const u16* An = Ab + (size_t)(kt + 1) * 32;
      const u16* Bn = Bb + (size_t)(kt + 1) * 32;
      u16* Asn = &As[cur ^ 1][0];
      u16* Bsn = &Bs[cur ^ 1][0];
      async16(An,         Asn + tid * 8);
      async16(An + rstep, Asn + 2048 + tid * 8);
      async16(Bn,         Bsn + tid * 8);
      async16(Bn + rstep, Bsn + 2048 + tid * 8);
    }
    bf16x8 af[4], bfv[4];
#pragma unroll
    for (int i = 0; i < 4; ++i)
      af[i] = *(const bf16x8*)&As[cur][(wm + i * 16 + lr) * 32 + lk * 8];
#pragma unroll
    for (int j = 0; j < 4; ++j)
      bfv[j] = *(const bf16x8*)&Bs[cur][(wn + j * 16 + lr) * 32 + lk * 8];
#pragma unroll
    for (int i = 0; i < 4; ++i)
#pragma unroll
      for (int j = 0; j < 4; ++j)
        acc[i][j] = mfma16(af[i], bfv[j], acc[i][j]);
    cur ^= 1;
  }

  const int gm0 = bm * 128 + wm, gn0 = bn * 128 + wn;
  float* outf = (float*)out;
  u16*   outb = (u16*)out;
#pragma unroll
  for (int i = 0; i < 4; ++i){
#pragma unroll
    for (int j = 0; j < 4; ++j){
      const int col = gn0 + j * 16 + lr;
      const float bv = bias ? bias[col] : 0.f;
#pragma unroll
      for (int r = 0; r < 4; ++r){
        const int row = gm0 + i * 16 + lk * 4 + r;
        const size_t idx = (size_t)row * N + col;
        float v = acc[i][j][r] + bv;
        if (fuse == 1)      v = fmaxf(v, 0.f);
        else if (fuse == 2) v = 0.5f * v * (1.f + erff(v * 0.70710678118654752f));
        else if (fuse == 4) v += resid[idx];
        else if (fuse == 5) v += resid[idx] + pos[((row & 31) << 10) + col];
        if (fuse >= 3) outf[idx] = v;
        else           outb[idx] = f2bf(v);
      }
    }
  }
}

// ---------------- big GEMM: 256x256 tile, 8 waves, 4-phase K-tiles, counted vmcnt ----
// Requires M%256==0, N%256==0, K%64==0, K>=128.
// LDS: A,B each [2 dbuf][2 half][128*64] bf16 = 128 KiB total. st_16x32 swizzle:
// linear LDS dest for global_load_lds + inverse-swizzled GLOBAL source + swizzled read.
// Schedule per K-tile t (buf p=t&1): readers of region R finish (lgkmcnt(0)+barrier)
// BEFORE any wave issues the stage overwriting R (B: read ph1-2, staged ph3; A: read
// ph1,ph3, staged ph4). vmcnt(8) per tile (never 0 mid-loop): next-next tile's 8 loads
// stay in flight across the barrier; per-wave vmcnt BEFORE s_barrier makes cooperative
// staging collectively visible.

#define QUAD256(mh, nh)                                                        \
  { _Pragma("unroll") for (int mi = 0; mi < 4; ++mi)                           \
    _Pragma("unroll") for (int nj = 0; nj < 2; ++nj)                           \
      _Pragma("unroll") for (int s = 0; s < 2; ++s)                            \
        acc[(mh)*4+mi][(nh)*2+nj] =                                            \
          mfma16(af[mi][s], bq[(nh)*2+nj][s], acc[(mh)*4+mi][(nh)*2+nj]); }

__global__ __launch_bounds__(512, 2) void gemm256(
    const u16* __restrict__ A, const u16* __restrict__ BT,
    const float* __restrict__ bias, const float* __restrict__ resid,
    const float* __restrict__ pos, void* __restrict__ out,
    int M, int N, int K, int fuse)
{
  __shared__ u16 Al[2][2][8192];
  __shared__ u16 Bl[2][2][8192];
  const int tid = threadIdx.x;

  const int nbn = gridDim.x, nwg = gridDim.x * gridDim.y;
  const int lid = blockIdx.y * nbn + blockIdx.x;
  const int q8 = nwg >> 3, r8 = nwg & 7;
  const int xcd = lid & 7, posi = lid >> 3;
  const int swz = (xcd < r8 ? xcd * (q8 + 1) : r8 * (q8 + 1) + (xcd - r8) * q8) + posi;
  const int bm = swz / nbn, bn = swz - bm * nbn;

  const int lane = tid & 63, wid = tid >> 6;
  const int wm = wid >> 2, wn = wid & 3;       // 2 (M) x 4 (N) waves
  const int lr = lane & 15, lk = lane >> 4;
  const int brow = (wn & 1) * 64;              // B local row base within its half

  f32x4 acc[8][4] = {};
  bf16x8 af[4][2], bq[4][2];

  const int nt = K >> 6;

  auto stageA = [&](int buf, int kt){
#pragma unroll
    for (int h = 0; h < 2; ++h){
      const char* g = (const char*)(A + (size_t)(bm * 256 + h * 128) * K + kt * 64);
      char* l = (char*)&Al[buf][h][0];
#pragma unroll
      for (int j = 0; j < 2; ++j){
        const int L = (j * 512 + tid) * 16;
        const int lg = SWZ(L);
        async16(g + (size_t)(lg >> 7) * ((size_t)K * 2) + (lg & 127), l + L);
      }
    }
  };
  auto stageB = [&](int buf, int kt){
#pragma unroll
    for (int h = 0; h < 2; ++h){
      const char* g = (const char*)(BT + (size_t)(bn * 256 + h * 128) * K + kt * 64);
      char* l = (char*)&Bl[buf][h][0];
#pragma unroll
      for (int j = 0; j < 2; ++j){
        const int L = (j * 512 + tid) * 16;
        const int lg = SWZ(L);
        async16(g + (size_t)(lg >> 7) * ((size_t)K * 2) + (lg & 127), l + L);
      }
    }
  };

  // prologue: tiles 0 and 1; wait tile 0 (own 8 oldest loads), tile 1 in flight
  stageA(0, 0); stageB(0, 0);
  stageA(1, 1); stageB(1, 1);
  asm volatile("s_waitcnt vmcnt(8)" ::: "memory");
  __builtin_amdgcn_s_barrier();

  for (int t = 0; t < nt; ++t){
    const int p = t & 1;
    const char* Ab = (const char*)&Al[p][wm][0];
    const char* Bb = (const char*)&Bl[p][wn >> 1][0];

    // ---- phase 1: read A-low + B-low; MFMA quadrant (0,0)
#pragma unroll
    for (int mi = 0; mi < 4; ++mi)
#pragma unroll
      for (int s = 0; s < 2; ++s){
        const int lg = (mi * 16 + lr) * 128 + s * 64 + lk * 16;
        af[mi][s] = *(const bf16x8*)(Ab + SWZ(lg));
      }
#pragma unroll
    for (int nj = 0; nj < 2; ++nj)
#pragma unroll
      for (int s = 0; s < 2; ++s){
        const int lg = (brow + nj * 16 + lr) * 128 + s * 64 + lk * 16;
        bq[nj][s] = *(const bf16x8*)(Bb + SWZ(lg));
      }
    __builtin_amdgcn_s_barrier();
    asm volatile("s_waitcnt lgkmcnt(0)" ::: "memory");
    __builtin_amdgcn_sched_barrier(0);
    __builtin_amdgcn_s_setprio(1);
    QUAD256(0, 0);
    __builtin_amdgcn_s_setprio(0);
    __builtin_amdgcn_sched_barrier(0);
    __builtin_amdgcn_s_barrier();

    // ---- phase 2: read B-high; MFMA (0,1)
#pragma unroll
    for (int nj = 0; nj < 2; ++nj)
#pragma unroll
      for (int s = 0; s < 2; ++s){
        const int lg = (brow + 32 + nj * 16 + lr) * 128 + s * 64 + lk * 16;
        bq[2 + nj][s] = *(const bf16x8*)(Bb + SWZ(lg));
      }
    __builtin_amdgcn_s_barrier();
    asm volatile("s_waitcnt lgkmcnt(0)" ::: "memory");
    __builtin_amdgcn_sched_barrier(0);
    __builtin_amdgcn_s_setprio(1);
    QUAD256(0, 1);
    __builtin_amdgcn_s_setprio(0);
    __builtin_amdgcn_sched_barrier(0);
    __builtin_amdgcn_s_barrier();

    // ---- phase 3: read A-high; stage B of tile t+2 (B of buf p fully read at ph2 barrier)
#pragma unroll
    for (int mi = 0; mi < 4; ++mi)
#pragma unroll
      for (int s = 0; s < 2; ++s){
        const int lg = (64 + mi * 16 + lr) * 128 + s * 64 + lk * 16;
        af[mi][s] = *(const bf16x8*)(Ab + SWZ(lg));
      }
    if (t + 2 < nt) stageB(p, t + 2);
    __builtin_amdgcn_s_barrier();
    asm volatile("s_waitcnt lgkmcnt(0)" ::: "memory");
    __builtin_amdgcn_sched_barrier(0);
    __builtin_amdgcn_s_setprio(1);
    QUAD256(1, 0);
    __builtin_amdgcn_s_setprio(0);
    __builtin_amdgcn_sched_barrier(0);
    __builtin_amdgcn_s_barrier();

    // ---- phase 4: stage A of tile t+2 (A of buf p fully read at ph3 barrier); MFMA (1,1)
    if (t + 2 < nt) stageA(p, t + 2);
    __builtin_amdgcn_s_barrier();
    __builtin_amdgcn_s_setprio(1);
    QUAD256(1, 1);
    __builtin_amdgcn_s_setprio(0);
    __builtin_amdgcn_sched_barrier(0);
    if (t + 2 < nt)      asm volatile("s_waitcnt vmcnt(8)" ::: "memory");
    else if (t + 1 < nt) asm volatile("s_waitcnt vmcnt(0)" ::: "memory");
    __builtin_amdgcn_sched_barrier(0);
    __builtin_amdgcn_s_barrier();
  }

  // ---- epilogue
  const int gm0 = bm * 256 + wm * 128, gn0 = bn * 256 + wn * 64;
  float* outf = (float*)out;
  u16*   outb = (u16*)out;
  float bv[4];
#pragma unroll
  for (int j = 0; j < 4; ++j) bv[j] = bias ? bias[gn0 + j * 16 + lr] : 0.f;
#pragma unroll
  for (int m = 0; m < 8; ++m){
#pragma unroll
    for (int j = 0; j < 4; ++j){
      const int col = gn0 + j * 16 + lr;
#pragma unroll
      for (int r = 0; r < 4; ++r){
        const int row = gm0 + m * 16 + lk * 4 + r;
        const size_t idx = (size_t)row * N + col;
        float v = acc[m][j][r] + bv[j];
        if (fuse == 1)      v = fmaxf(v, 0.f);
        else if (fuse == 2) v = 0.5f * v * (1.f + erff(v * 0.70710678118654752f));
        else if (fuse == 4) v += resid[idx];
        else if (fuse == 5) v += resid[idx] + pos[((row & 31) << 10) + col];
        if (fuse >= 3) outf[idx] = v;
        else           outb[idx] = f2bf(v);
      }
    }
  }
}

// ---------------- LayerNorm: fp32 in -> bf16 out ----------------

__global__ __launch_bounds__(256) void ln_k(
    const float* __restrict__ x, const float* __restrict__ g,
    const float* __restrict__ b, u16* __restrict__ out)
{
  const int row = blockIdx.x;
  const float* xr = x + (size_t)row * 1024;
  const int tid = threadIdx.x;
  float4 v = *(const float4*)(xr + tid * 4);
  float s  = v.x + v.y + v.z + v.w;
  float ss = v.x * v.x + v.y * v.y + v.z * v.z + v.w * v.w;
#pragma unroll
  for (int m = 1; m < 64; m <<= 1){ s += __shfl_xor(s, m, 64); ss += __shfl_xor(ss, m, 64); }
  __shared__ float red[8];
  if ((tid & 63) == 0){ red[tid >> 6] = s; red[4 + (tid >> 6)] = ss; }
  __syncthreads();
  s  = red[0] + red[1] + red[2] + red[3];
  ss = red[4] + red[5] + red[6] + red[7];
  const float mu = s * (1.f / 1024.f);
  const float rs = rsqrtf(ss * (1.f / 1024.f) - mu * mu + 1e-5f);
  float4 gg = *(const float4*)(g + tid * 4);
  float4 bb = *(const float4*)(b + tid * 4);
  short4 sv = make_short4((short)f2bf((v.x - mu) * rs * gg.x + bb.x),
                          (short)f2bf((v.y - mu) * rs * gg.y + bb.y),
                          (short)f2bf((v.z - mu) * rs * gg.z + bb.z),
                          (short)f2bf((v.w - mu) * rs * gg.w + bb.w));
  *(short4*)(out + (size_t)row * 1024 + tid * 4) = sv;
}

// ---------------- attention: one wave per (b,h), S=32, HD=64 ----------------
// QKV packed: row stride 3072; q at col h*64, k at +1024, v at +2048.

__global__ __launch_bounds__(256) void attn_k(
    const u16* __restrict__ QKV, const u16* __restrict__ rel,
    u16* __restrict__ O)
{
  __shared__ char smem[65536];
  const int tid = threadIdx.x;
  const int wid = tid >> 6, lane = tid & 63;
  const int lr = lane & 15, lk = lane >> 4;
  char* sw = smem + wid * 16384;
  float* P = (float*)sw;            // [32][68] f32
  u16*  AL = (u16*)(sw + 8704);     // [32][40] bf16 (attn probs)
  u16*  VT = (u16*)(sw + 11264);    // [64][40] bf16 (V^T)

  const int pair = blockIdx.x * 4 + wid;
  const int b = pair >> 4, h = pair & 15;
  const u16* q  = QKV + (size_t)b * 32 * 3072 + (size_t)h * 64;
  const u16* kk = q + 1024;
  const u16* v  = q + 2048;
  u16* o = O + (size_t)b * 32768 + (size_t)h * 64;

  s16x8 vv[4];
#pragma unroll
  for (int j = 0; j < 4; ++j){
    const int e = j * 64 + lane;
    const int ki = e >> 3, d0 = (e & 7) * 8;
    vv[j] = *(const s16x8*)(v + (size_t)ki * 3072 + d0);
  }

  bf16x8 qf[2][2], kf[2][2];
#pragma unroll
  for (int mf = 0; mf < 2; ++mf)
#pragma unroll
    for (int ks = 0; ks < 2; ++ks){
      qf[mf][ks] = *(const bf16x8*)(q  + (size_t)(mf * 16 + lr) * 3072 + ks * 32 + lk * 8);
      kf[mf][ks] = *(const bf16x8*)(kk + (size_t)(mf * 16 + lr) * 3072 + ks * 32 + lk * 8);
    }

  f32x4 sc[2][2] = {};
#pragma unroll
  for (int mf = 0; mf < 2; ++mf)
#pragma unroll
    for (int nf = 0; nf < 2; ++nf){
      sc[mf][nf] = mfma16(qf[mf][0], kf[nf][0], sc[mf][nf]);
      sc[mf][nf] = mfma16(qf[mf][1], kf[nf][1], sc[mf][nf]);
      sc[mf][nf] *= 0.125f;  // 1/sqrt(64), QK^T only
    }

  f32x4 p[2][4] = {};
#pragma unroll
  for (int nf = 0; nf < 4; ++nf){
    bf16x8 rf0 = *(const bf16x8*)(rel + (nf * 16 + lr) * 64 + lk * 8);
    bf16x8 rf1 = *(const bf16x8*)(rel + (nf * 16 + lr) * 64 + 32 + lk * 8);
#pragma unroll
    for (int mf = 0; mf < 2; ++mf){
      p[mf][nf] = mfma16(qf[mf][0], rf0, p[mf][nf]);
      p[mf][nf] = mfma16(qf[mf][1], rf1, p[mf][nf]);
    }
  }

  // stage V^T (padded stride 40)
#pragma unroll
  for (int j = 0; j < 4; ++j){
    const int e = j * 64 + lane;
    const int ki = e >> 3, d0 = (e & 7) * 8;
#pragma unroll
    for (int i = 0; i < 8; ++i)
      VT[(d0 + i) * 40 + ki] = (u16)vv[j][i];
  }
  // stage P [32][68]
#pragma unroll
  for (int mf = 0; mf < 2; ++mf)
#pragma unroll
    for (int nf = 0; nf < 4; ++nf)
#pragma unroll
      for (int r = 0; r < 4; ++r)
        P[(mf * 16 + lk * 4 + r) * 68 + nf * 16 + lr] = p[mf][nf][r];

  __syncthreads();

  // scores += P[q, q-k+32]
#pragma unroll
  for (int mf = 0; mf < 2; ++mf)
#pragma unroll
    for (int n2 = 0; n2 < 2; ++n2)
#pragma unroll
      for (int r = 0; r < 4; ++r){
        const int qr = mf * 16 + lk * 4 + r;
        const int kc = n2 * 16 + lr;
        sc[mf][n2][r] += P[qr * 68 + (qr - kc + 32)];
      }

  // softmax per row
#pragma unroll
  for (int mf = 0; mf < 2; ++mf)
#pragma unroll
    for (int r = 0; r < 4; ++r){
      float mx = fmaxf(sc[mf][0][r], sc[mf][1][r]);
#pragma unroll
      for (int m2 = 1; m2 < 16; m2 <<= 1) mx = fmaxf(mx, __shfl_xor(mx, m2, 64));
      const float e0 = __expf(sc[mf][0][r] - mx);
      const float e1 = __expf(sc[mf][1][r] - mx);
      float sm = e0 + e1;
#pragma unroll
      for (int m2 = 1; m2 < 16; m2 <<= 1) sm += __shfl_xor(sm, m2, 64);
      const float inv = 1.f / sm;
      sc[mf][0][r] = e0 * inv;
      sc[mf][1][r] = e1 * inv;
    }

#pragma unroll
  for (int mf = 0; mf < 2; ++mf)
#pragma unroll
    for (int n2 = 0; n2 < 2; ++n2)
#pragma unroll
      for (int r = 0; r < 4; ++r)
        AL[(mf * 16 + lk * 4 + r) * 40 + n2 * 16 + lr] = f2bf(sc[mf][n2][r]);

  __syncthreads();

  bf16x8 paf[2];
  paf[0] = *(const bf16x8*)&AL[(lr) * 40 + lk * 8];
  paf[1] = *(const bf16x8*)&AL[(16 + lr) * 40 + lk * 8];

  f32x4 of[2][4] = {};
#pragma unroll
  for (int nf = 0; nf < 4; ++nf){
    bf16x8 vf = *(const bf16x8*)&VT[(nf * 16 + lr) * 40 + lk * 8];
    of[0][nf] = mfma16(paf[0], vf, of[0][nf]);
    of[1][nf] = mfma16(paf[1], vf, of[1][nf]);
  }
#pragma unroll
  for (int mf = 0; mf < 2; ++mf)
#pragma unroll
    for (int nf = 0; nf < 4; ++nf)
#pragma unroll
      for (int r = 0; r < 4; ++r)
        o[(size_t)(mf * 16 + lk * 4 + r) * 1024 + nf * 16 + lr] = f2bf(of[mf][nf][r]);
}

// ---------------- final act MLP helpers ----------------

__global__ void gather_last(const float* __restrict__ x, u16* __restrict__ out){
  const int i = blockIdx.x * 256 + threadIdx.x;   // 512*1024
  const int b = i >> 10, c = i & 1023;
  out[i] = f2bf(x[((size_t)b * 32 + 31) * 1024 + c]);
}

// fuse: 1 relu->bf16, 3 bias->f32
__global__ void small_gemm(const u16* __restrict__ A, const u16* __restrict__ BT,
                           const float* __restrict__ bias, void* __restrict__ out,
                           int M, int N, int K, int fuse){
  const int idx = blockIdx.x * 256 + threadIdx.x;
  if (idx >= M * N) return;
  const int m = idx / N, n = idx - m * N;
  const u16* a  = A  + (size_t)m * K;
  const u16* bt = BT + (size_t)n * K;
  float acc = 0.f;
  for (int k = 0; k < K; k += 8){
    s16x8 av = *(const s16x8*)(a + k);
    s16x8 bv = *(const s16x8*)(bt + k);
#pragma unroll
    for (int i = 0; i < 8; ++i) acc += bf2f((u16)av[i]) * bf2f((u16)bv[i]);
  }
  float v = acc + bias[n];
  if (fuse == 1) v = fmaxf(v, 0.f);
  if (fuse == 3) ((float*)out)[idx] = v;
  else           ((u16*)out)[idx]   = f2bf(v);
}

// ---------------- host ----------------

extern "C" void kernel_launch(void* const* d_in, const int* in_sizes, int n_in,
                              void* d_out, int out_size, void* d_ws, size_t ws_size,
                              hipStream_t stream)
{
  (void)in_sizes; (void)n_in; (void)out_size;
  const float* obs    = (const float*)d_in[0];
  const float* refp   = (const float*)d_in[1];
  const float* obs_w0 = (const float*)d_in[2];
  const float* obs_b0 = (const float*)d_in[3];
  const float* obs_w1 = (const float*)d_in[4];
  const float* obs_b1 = (const float*)d_in[5];
  const float* obs_w2 = (const float*)d_in[6];
  const float* obs_b2 = (const float*)d_in[7];
  const float* ref_w0 = (const float*)d_in[8];
  const float* ref_b0 = (const float*)d_in[9];
  const float* ref_w1 = (const float*)d_in[10];
  const float* ref_b1 = (const float*)d_in[11];
  const float* ref_w2 = (const float*)d_in[12];
  const float* ref_b2 = (const float*)d_in[13];
  const float* pos    = (const float*)d_in[14];
  const float* Wq     = (const float*)d_in[15];
  const float* Wk     = (const float*)d_in[16];
  const float* Wv     = (const float*)d_in[17];
  const float* Wo     = (const float*)d_in[18];
  const float* bo     = (const float*)d_in[19];
  const float* rel    = (const float*)d_in[20];
  const float* ff_w1  = (const float*)d_in[21];
  const float* ff_b1  = (const float*)d_in[22];
  const float* ff_w2  = (const float*)d_in[23];
  const float* ff_b2  = (const float*)d_in[24];
  const float* ln1g   = (const float*)d_in[25];
  const float* ln1b   = (const float*)d_in[26];
  const float* ln2g   = (const float*)d_in[27];
  const float* ln2b   = (const float*)d_in[28];
  const float* act_w0 = (const float*)d_in[29];
  const float* act_b0 = (const float*)d_in[30];
  const float* act_w1 = (const float*)d_in[31];
  const float* act_b1 = (const float*)d_in[32];
  const float* act_w2 = (const float*)d_in[33];
  const float* act_b2 = (const float*)d_in[34];
  float* outp = (float*)d_out;

  char* wsp = (char*)d_ws; size_t off = 0;
  auto alloc = [&](size_t bytes)->char*{ char* p = wsp + off;
                                         off = (off + bytes + 255) & ~(size_t)255; return p; };

  // persistent small weights (~2.4 MB)
  u16* wt_obs0 = (u16*)alloc((size_t)512 * 256 * 2);
  u16* wt_obs1 = (u16*)alloc((size_t)256 * 512 * 2);
  u16* wt_obs2 = (u16*)alloc((size_t)1024 * 256 * 2);
  u16* wt_ref0 = (u16*)alloc((size_t)256 * 128 * 2);
  u16* wt_ref1 = (u16*)alloc((size_t)256 * 256 * 2);
  u16* wt_ref2 = (u16*)alloc((size_t)1024 * 256 * 2);
  u16* wt_a0   = (u16*)alloc((size_t)256 * 1024 * 2);
  u16* wt_a1   = (u16*)alloc((size_t)128 * 256 * 2);
  u16* wt_a2   = (u16*)alloc((size_t)32 * 128 * 2);
  u16* rel_bf  = (u16*)alloc((size_t)6 * 65 * 64 * 2);
  // per-layer weight buffers (reused each layer)
  u16* wt_qkv  = (u16*)alloc((size_t)3072 * 1024 * 2);   // rows: [Wq^T; Wk^T; Wv^T]
  u16* wt_lo   = (u16*)alloc((size_t)1024 * 1024 * 2);
  u16* wt_lf1  = (u16*)alloc((size_t)2048 * 1024 * 2);
  u16* wt_lf2  = (u16*)alloc((size_t)2048 * 1024 * 2);
  // activations
  float* x     = (float*)alloc((size_t)16384 * 1024 * 4);   // 67 MB, fp32 residual
  u16* xn      = (u16*)alloc((size_t)16384 * 1024 * 2);     // 33.5 MB
  u16* qkv     = (u16*)alloc((size_t)16384 * 3072 * 2);     // 100.7 MB

  if (off > ws_size) return;  // clean diagnostic failure instead of a GPU fault

  // aliases (stream-order-safe):
  u16* obs_bf = qkv;                              // embed phase only
  u16* h1     = qkv + (size_t)16384 * 256;        // [16384,512]
  u16* h2     = qkv + (size_t)16384 * 768;        // [16384,256]
  u16* ref_bf = xn;
  u16* ob     = xn;                               // attn out: xn dead after qkv GEMM
  u16* ffb    = qkv;                              // ff hidden [16384,2048], qkv dead during FF
  u16* xlast  = qkv;                              // after last layer
  u16* a1b    = qkv + (size_t)16384 * 256;
  u16* a2b    = qkv + (size_t)16384 * 512;

  auto CV = [&](const float* src, u16* dst, int n){
    cvt_bf16<<<dim3((n / 4 + 255) / 256), dim3(256), 0, stream>>>(src, dst, n);
  };
  auto TR = [&](const float* W, u16* WT, int Kd, int Nd, int nz){
    trans_w<<<dim3(Nd / 32, Kd / 32, nz), dim3(32, 8), 0, stream>>>(W, WT, Kd, Nd);
  };
  auto GM = [&](const u16* A, const u16* BT, const float* bias, const float* resid,
                const float* posb, void* op, int Md, int Nd, int Kd, int fuse){
    gemm128<<<dim3(Nd / 128, Md / 128), dim3(256), 0, stream>>>(A, BT, bias, resid, posb, op, Md, Nd, Kd, fuse);
  };
  auto GM2 = [&](const u16* A, const u16* BT, const float* bias, const float* resid,
                 const float* posb, void* op, int Md, int Nd, int Kd, int fuse){
    gemm256<<<dim3(Nd / 256, Md / 256), dim3(512), 0, stream>>>(A, BT, bias, resid, posb, op, Md, Nd, Kd, fuse);
  };

  // small weight prep
  CV(rel, rel_bf, 6 * 65 * 64);
  TR(obs_w0, wt_obs0, 256, 512, 1);
  TR(obs_w1, wt_obs1, 512, 256, 1);
  TR(obs_w2, wt_obs2, 256, 1024, 1);
  TR(ref_w0, wt_ref0, 128, 256, 1);
  TR(ref_w1, wt_ref1, 256, 256, 1);
  TR(ref_w2, wt_ref2, 256, 1024, 1);
  TR(act_w0, wt_a0, 1024, 256, 1);
  TR(act_w1, wt_a1, 256, 128, 1);
  TR(act_w2, wt_a2, 128, 32, 1);

  const int M = 16384;
  // embed: x = mlp3(obs) + mlp3(ref) + pos
  CV(obs, obs_bf, 16384 * 256);
  GM(obs_bf, wt_obs0, obs_b0, nullptr, nullptr, h1, M, 512, 256, 1);
  GM(h1,     wt_obs1, obs_b1, nullptr, nullptr, h2, M, 256, 512, 1);
  GM2(h2,    wt_obs2, obs_b2, nullptr, nullptr, x,  M, 1024, 256, 3);
  CV(refp, ref_bf, 16384 * 128);
  GM(ref_bf, wt_ref0, ref_b0, nullptr, nullptr, h2, M, 256, 128, 1);
  GM(h2,     wt_ref1, ref_b1, nullptr, nullptr, h1, M, 256, 256, 1);
  GM2(h1,    wt_ref2, ref_b2, x, pos,           x,  M, 1024, 256, 5);

  for (int l = 0; l < 6; ++l){
    // per-layer weight conversion into the shared buffers
    TR(Wq + (size_t)l * 1048576, wt_qkv,                        1024, 1024, 1);
    TR(Wk + (size_t)l * 1048576, wt_qkv + (size_t)1024 * 1024,  1024, 1024, 1);
    TR(Wv + (size_t)l * 1048576, wt_qkv + (size_t)2048 * 1024,  1024, 1024, 1);
    TR(Wo + (size_t)l * 1048576, wt_lo, 1024, 1024, 1);
    TR(ff_w1 + (size_t)l * 2097152, wt_lf1, 1024, 2048, 1);
    TR(ff_w2 + (size_t)l * 2097152, wt_lf2, 2048, 1024, 1);

    ln_k<<<dim3(16384), dim3(256), 0, stream>>>(x, ln1g + l * 1024, ln1b + l * 1024, xn);
    GM2(xn, wt_qkv, nullptr, nullptr, nullptr, qkv, M, 3072, 1024, 0);
    attn_k<<<dim3(2048), dim3(256), 0, stream>>>(qkv, rel_bf + (size_t)l * 4160, ob);
    GM2(ob, wt_lo, bo + l * 1024, x, nullptr, x, M, 1024, 1024, 4);
    ln_k<<<dim3(16384), dim3(256), 0, stream>>>(x, ln2g + l * 1024, ln2b + l * 1024, xn);
    GM2(xn,  wt_lf1, ff_b1 + l * 2048, nullptr, nullptr, ffb, M, 2048, 1024, 2);
    GM2(ffb, wt_lf2, ff_b2 + l * 1024, x, nullptr, x, M, 1024, 2048, 4);
  }

  gather_last<<<dim3(2048), dim3(256), 0, stream>>>(x, xlast);
  small_gemm<<<dim3(512 * 256 / 256), dim3(256), 0, stream>>>(xlast, wt_a0, act_b0, a1b, 512, 256, 1024, 1);
  small_gemm<<<dim3(512 * 128 / 256), dim3(256), 0, stream>>>(a1b, wt_a1, act_b1, a2b, 512, 128, 256, 1);
  small_gemm<<<dim3(512 * 32 / 256),  dim3(256), 0, stream>>>(a2b, wt_a2, act_b2, outp, 512, 32, 128, 3);
}